// Round 11
// baseline (555.805 us; speedup 1.0000x reference)
//
#include <hip/hip_runtime.h>

#define N_NODES  100000
#define N_EDGES  1600000
#define DIM      64
#define N_GRAPHS 128
#define OUT_DIM  10
#define SCAN_NB    196
#define SCAN_CHUNK 512      // 196*512 = 100352 >= N_NODES
#define RANGE_BITS 14
#define RANGE_SIZE 16384    // nodes per dst-range
#define N_RANGES   7        // 7*16384 = 114688 >= N_NODES
#define N_CHUNKS   32
#define CHUNK_EDGES (N_EDGES / N_CHUNKS)   // 50000
#define NODE_PAD   (N_RANGES * RANGE_SIZE) // 114688

typedef unsigned int uint;
typedef unsigned short ushort;
typedef __attribute__((ext_vector_type(8))) short short8;   // 8 bf16 = 4 VGPRs
typedef __attribute__((ext_vector_type(4))) float f32x4;

__device__ __forceinline__ uint f2bf(float x) {   // fp32 -> bf16 bits (RNE)
    uint b = __float_as_uint(x);
    b += 0x7fffu + ((b >> 16) & 1u);
    return b >> 16;
}

// ---------------- CSR build, NO global atomics, XCD-co-located chunks ----------
// WG mapping: c = blockIdx % 32, r = blockIdx / 32. XCD = blockIdx % 8 = c % 8,
// so all 8 range-WGs of a chunk run on ONE XCD -> chunk's dst/src fetched from
// HBM once, re-read as L2 hits (R10: 8 XCDs each fetched it -> 49MB FETCH).

__global__ __launch_bounds__(1024) void histo_kernel(const int* __restrict__ dst,
                                                     int* __restrict__ counts8) {
    __shared__ int lds[RANGE_SIZE];
    const int c = blockIdx.x & (N_CHUNKS - 1);
    const int r = blockIdx.x >> 5;
    if (r >= N_RANGES) return;
    for (int j = threadIdx.x; j < RANGE_SIZE; j += 1024) lds[j] = 0;
    __syncthreads();
    const int beg = c * CHUNK_EDGES, end = beg + CHUNK_EDGES;
    for (int i = beg + threadIdx.x; i < end; i += 1024) {
        int d = dst[i];
        if ((d >> RANGE_BITS) == r) atomicAdd(&lds[d & (RANGE_SIZE - 1)], 1);
    }
    __syncthreads();
    int* outp = counts8 + (c * N_RANGES + r) * RANGE_SIZE;   // contiguous 64KB dump
    for (int j = threadIdx.x; j < RANGE_SIZE; j += 1024) outp[j] = lds[j];
}

__global__ void scanA_kernel(const int* __restrict__ counts8, int* __restrict__ blockSums, int n) {
    __shared__ int red[256];
    const int b = blockIdx.x, t = threadIdx.x;
    int s = 0;
#pragma unroll
    for (int k = 0; k < 2; ++k) {
        const int node = b * SCAN_CHUNK + t * 2 + k;
        if (node < n) {
            const int r = node >> RANGE_BITS, jj = node & (RANGE_SIZE - 1);
            for (int c = 0; c < N_CHUNKS; ++c)
                s += counts8[(c * N_RANGES + r) * RANGE_SIZE + jj];
        }
    }
    red[t] = s;
    __syncthreads();
    for (int off = 128; off > 0; off >>= 1) {
        if (t < off) red[t] += red[t + off];
        __syncthreads();
    }
    if (t == 0) blockSums[b] = red[0];
}

__global__ void scanB_kernel(const int* __restrict__ blockSums, int* __restrict__ blockOffs,
                             int* __restrict__ row_ptr) {
    __shared__ int sc[256];
    const int t = threadIdx.x;
    const int v = (t < SCAN_NB) ? blockSums[t] : 0;
    sc[t] = v;
    __syncthreads();
    for (int off = 1; off < 256; off <<= 1) {
        int u = (t >= off) ? sc[t - off] : 0;
        __syncthreads();
        sc[t] += u;
        __syncthreads();
    }
    if (t < SCAN_NB) blockOffs[t] = sc[t] - v;   // exclusive block offset
    if (t == 255) row_ptr[N_NODES] = sc[255];    // total == N_EDGES
}

// row_ptr + per-chunk slot bases base8[c][node]
__global__ void scanC_kernel(const int* __restrict__ counts8, const int* __restrict__ blockOffs,
                             int* __restrict__ row_ptr, int* __restrict__ base8, int n) {
    __shared__ int sc[256];
    const int b = blockIdx.x, t = threadIdx.x;
    const int node0 = b * SCAN_CHUNK + t * 2;
    int cnt0[N_CHUNKS], cnt1[N_CHUNKS];
    int tot0 = 0, tot1 = 0;
    if (node0 < n) {
        const int r = node0 >> RANGE_BITS, jj = node0 & (RANGE_SIZE - 1);
        for (int c = 0; c < N_CHUNKS; ++c) {
            cnt0[c] = counts8[(c * N_RANGES + r) * RANGE_SIZE + jj];
            tot0 += cnt0[c];
        }
    }
    if (node0 + 1 < n) {
        const int r = (node0 + 1) >> RANGE_BITS, jj = (node0 + 1) & (RANGE_SIZE - 1);
        for (int c = 0; c < N_CHUNKS; ++c) {
            cnt1[c] = counts8[(c * N_RANGES + r) * RANGE_SIZE + jj];
            tot1 += cnt1[c];
        }
    }
    const int s = tot0 + tot1;
    sc[t] = s;
    __syncthreads();
    for (int off = 1; off < 256; off <<= 1) {
        int u = (t >= off) ? sc[t - off] : 0;
        __syncthreads();
        sc[t] += u;
        __syncthreads();
    }
    const int pre = blockOffs[b] + sc[t] - s;    // exclusive prefix for node0
    if (node0 < n) {
        row_ptr[node0] = pre;
        int run = pre;
        for (int c = 0; c < N_CHUNKS; ++c) { base8[c * NODE_PAD + node0] = run; run += cnt0[c]; }
    }
    if (node0 + 1 < n) {
        const int pre1 = pre + tot0;
        row_ptr[node0 + 1] = pre1;
        int run = pre1;
        for (int c = 0; c < N_CHUNKS; ++c) { base8[c * NODE_PAD + node0 + 1] = run; run += cnt1[c]; }
    }
}

__global__ __launch_bounds__(1024) void fill_kernel(const int* __restrict__ src,
                                                    const int* __restrict__ dst,
                                                    const int* __restrict__ base8,
                                                    int* __restrict__ col_idx) {
    __shared__ int lds[RANGE_SIZE];
    const int c = blockIdx.x & (N_CHUNKS - 1);
    const int r = blockIdx.x >> 5;
    if (r >= N_RANGES) return;
    const int* bp = base8 + c * NODE_PAD + r * RANGE_SIZE;
    for (int j = threadIdx.x; j < RANGE_SIZE; j += 1024) lds[j] = bp[j];
    __syncthreads();
    const int beg = c * CHUNK_EDGES, end = beg + CHUNK_EDGES;
    for (int i = beg + threadIdx.x; i < end; i += 1024) {
        int d = dst[i];
        if ((d >> RANGE_BITS) == r) {
            int pos = atomicAdd(&lds[d & (RANGE_SIZE - 1)], 1);
            col_idx[pos] = src[i];
        }
    }
}

// ---------------- x (fp32) -> bf16 rows ----------------

__global__ void cvt_kernel(const float* __restrict__ x, ushort* __restrict__ xb, int n4) {
    int idx = blockIdx.x * blockDim.x + threadIdx.x;
    if (idx >= n4) return;
    float4 v = ((const float4*)x)[idx];
    uint2 o;
    o.x = f2bf(v.x) | (f2bf(v.y) << 16);
    o.y = f2bf(v.z) | (f2bf(v.w) << 16);
    ((uint2*)xb)[idx] = o;
}

// ---------------- Weight repack: MFMA fragment layouts, once per launch ----------

__global__ void repack_kernel(const float* __restrict__ W1, const float* __restrict__ W2,
                              uint4* __restrict__ Wp) {
    const int wave = (blockIdx.x * blockDim.x + threadIdx.x) >> 6;
    if (wave >= 10) return;
    const int layer = wave >> 1;
    const float* W = (wave & 1) ? (W2 + layer * 4096) : (W1 + layer * 4096);
    const int lane = threadIdx.x & 63;
    const int n15 = lane & 15, quad = lane >> 4;
#pragma unroll
    for (int f = 0; f < 8; ++f) {
        const int outer = f >> 1, h = f & 1;
        uint p[4];
#pragma unroll
        for (int pj = 0; pj < 4; ++pj) {
            const int k0 = h * 32 + quad * 8 + 2 * pj;
            uint lo = f2bf(W[k0 * 64 + outer * 16 + n15]);
            uint hi = f2bf(W[(k0 + 1) * 64 + outer * 16 + n15]);
            p[pj] = lo | (hi << 16);
        }
        Wp[(wave * 8 + f) * 64 + lane] = make_uint4(p[0], p[1], p[2], p[3]);
    }
}

// ---------------- Aggregation: tb[i] = hb[i] + sum_{j in N(i)} hb[j] -> bf16 ------
// GROUP-PER-NODE: 8 lanes/node, 8 nodes/wave; unroll 8 -> 8 dwordx4 gathers
// in flight. launch_bounds(256,8) pins VGPR<=64 so 8 waves/SIMD survive.

__device__ __forceinline__ void add_unpack(float acc[8], uint4 v) {
    acc[0] += __uint_as_float(v.x << 16);
    acc[1] += __uint_as_float(v.x & 0xffff0000u);
    acc[2] += __uint_as_float(v.y << 16);
    acc[3] += __uint_as_float(v.y & 0xffff0000u);
    acc[4] += __uint_as_float(v.z << 16);
    acc[5] += __uint_as_float(v.z & 0xffff0000u);
    acc[6] += __uint_as_float(v.w << 16);
    acc[7] += __uint_as_float(v.w & 0xffff0000u);
}

__global__ __launch_bounds__(256, 8) void agg_kernel(
    const ushort* __restrict__ hb, ushort* __restrict__ tb,
    const int* __restrict__ row_ptr, const int* __restrict__ col_idx, int n)
{
    const uint4* __restrict__ hb4 = (const uint4*)hb;   // row = 8 uint4
    const int lane = threadIdx.x & 63;
    const int g = lane >> 3;     // node slot 0..7 within wave
    const int q = lane & 7;      // 16B chunk 0..7 within row
    const int wave = (blockIdx.x * blockDim.x + threadIdx.x) >> 6;
    const int i = wave * 8 + g;
    if (i >= n) return;
    const int rp0 = row_ptr[i];
    const int deg = row_ptr[i + 1] - rp0;

    float acc[8];
    {   // self term (eps = 0) — safe in init: no cross-lane reduction follows
        uint4 v = hb4[(size_t)i * 8 + q];
        acc[0] = __uint_as_float(v.x << 16);
        acc[1] = __uint_as_float(v.x & 0xffff0000u);
        acc[2] = __uint_as_float(v.y << 16);
        acc[3] = __uint_as_float(v.y & 0xffff0000u);
        acc[4] = __uint_as_float(v.z << 16);
        acc[5] = __uint_as_float(v.z & 0xffff0000u);
        acc[6] = __uint_as_float(v.w << 16);
        acc[7] = __uint_as_float(v.w & 0xffff0000u);
    }

    int e = 0;
    for (; e + 8 <= deg; e += 8) {   // 8 gathers in flight per group
        int ix[8];
#pragma unroll
        for (int k = 0; k < 8; ++k) ix[k] = col_idx[rp0 + e + k];
        uint4 v[8];
#pragma unroll
        for (int k = 0; k < 8; ++k) v[k] = hb4[(size_t)ix[k] * 8 + q];
#pragma unroll
        for (int k = 0; k < 8; ++k) add_unpack(acc, v[k]);
    }
    if (e + 4 <= deg) {
        int ix[4];
#pragma unroll
        for (int k = 0; k < 4; ++k) ix[k] = col_idx[rp0 + e + k];
        uint4 v[4];
#pragma unroll
        for (int k = 0; k < 4; ++k) v[k] = hb4[(size_t)ix[k] * 8 + q];
#pragma unroll
        for (int k = 0; k < 4; ++k) add_unpack(acc, v[k]);
        e += 4;
    }
    for (; e < deg; ++e) {
        int ix = col_idx[rp0 + e];
        uint4 v = hb4[(size_t)ix * 8 + q];
        add_unpack(acc, v);
    }

    uint4 o;   // pack 8 fp32 -> 8 bf16 (dims q*8 .. q*8+7)
    o.x = f2bf(acc[0]) | (f2bf(acc[1]) << 16);
    o.y = f2bf(acc[2]) | (f2bf(acc[3]) << 16);
    o.z = f2bf(acc[4]) | (f2bf(acc[5]) << 16);
    o.w = f2bf(acc[6]) | (f2bf(acc[7]) << 16);
    ((uint4*)tb)[(size_t)i * 8 + q] = o;
}

// ---------------- MLP via MFMA (R7 structure, unchanged) ----------------

__global__ __launch_bounds__(256) void mlp_kernel(
    const ushort* __restrict__ tb, ushort* __restrict__ hb,
    const uint4* __restrict__ Wp,   // layer frags: [0..7]=W1^T, [8..15]=W2
    const float* __restrict__ b1, const float* __restrict__ gamma,
    const float* __restrict__ beta, const float* __restrict__ rmean,
    const float* __restrict__ rvar, const float* __restrict__ b2, int ntiles)
{
    __shared__ __align__(16) ushort U[4][16][72];   // stride 72 breaks pow-2 banks
    const int lane = threadIdx.x & 63;
    const int wid  = threadIdx.x >> 6;
    const int n15  = lane & 15, quad = lane >> 4;

    short8 w1f[8], w2f[8];
    const short8* Wp8 = (const short8*)Wp;
#pragma unroll
    for (int f = 0; f < 8; ++f) {
        w1f[f] = Wp8[f * 64 + lane];
        w2f[f] = Wp8[(8 + f) * 64 + lane];
    }
    f32x4 sc[4], sh[4];
#pragma unroll
    for (int mt = 0; mt < 4; ++mt) {
        const int j0 = mt * 16 + quad * 4;
#pragma unroll
        for (int r = 0; r < 4; ++r) {
            float s = gamma[j0 + r] * rsqrtf(rvar[j0 + r] + 1e-5f);
            sc[mt][r] = s;
            sh[mt][r] = (b1[j0 + r] - rmean[j0 + r]) * s + beta[j0 + r];
        }
    }
    float bb2[4];
#pragma unroll
    for (int tc = 0; tc < 4; ++tc) bb2[tc] = b2[tc * 16 + n15];

    const int wave = blockIdx.x * 4 + wid;
    const int nwaves = gridDim.x * 4;
    for (int tile = wave; tile < ntiles; tile += nwaves) {
        const int nb = tile * 16;
        const short8* trow = (const short8*)(tb + (size_t)(nb + n15) * 64);
        short8 t0 = trow[quad];        // k = 0..31 half
        short8 t1 = trow[4 + quad];    // k = 32..63 half

        f32x4 c1[4];
#pragma unroll
        for (int mt = 0; mt < 4; ++mt) {
            c1[mt] = (f32x4){0.f, 0.f, 0.f, 0.f};
            c1[mt] = __builtin_amdgcn_mfma_f32_16x16x32_bf16(w1f[mt * 2 + 0], t0, c1[mt], 0, 0, 0);
            c1[mt] = __builtin_amdgcn_mfma_f32_16x16x32_bf16(w1f[mt * 2 + 1], t1, c1[mt], 0, 0, 0);
        }
#pragma unroll
        for (int mt = 0; mt < 4; ++mt) {
            float u0 = fmaxf(c1[mt][0] * sc[mt][0] + sh[mt][0], 0.f);
            float u1 = fmaxf(c1[mt][1] * sc[mt][1] + sh[mt][1], 0.f);
            float u2 = fmaxf(c1[mt][2] * sc[mt][2] + sh[mt][2], 0.f);
            float u3 = fmaxf(c1[mt][3] * sc[mt][3] + sh[mt][3], 0.f);
            uint2 pk;
            pk.x = f2bf(u0) | (f2bf(u1) << 16);
            pk.y = f2bf(u2) | (f2bf(u3) << 16);
            *(uint2*)&U[wid][n15][mt * 16 + quad * 4] = pk;
        }
        __threadfence_block();
        short8 u0 = *(const short8*)&U[wid][n15][quad * 8];
        short8 u1 = *(const short8*)&U[wid][n15][32 + quad * 8];

        f32x4 c2[4];
#pragma unroll
        for (int tc = 0; tc < 4; ++tc) {
            c2[tc] = (f32x4){0.f, 0.f, 0.f, 0.f};
            c2[tc] = __builtin_amdgcn_mfma_f32_16x16x32_bf16(u0, w2f[tc * 2 + 0], c2[tc], 0, 0, 0);
            c2[tc] = __builtin_amdgcn_mfma_f32_16x16x32_bf16(u1, w2f[tc * 2 + 1], c2[tc], 0, 0, 0);
        }
#pragma unroll
        for (int tc = 0; tc < 4; ++tc) {
#pragma unroll
            for (int r = 0; r < 4; ++r) {
                float v = fmaxf(c2[tc][r] + bb2[tc], 0.f);
                hb[(size_t)(nb + quad * 4 + r) * 64 + tc * 16 + n15] = (ushort)f2bf(v);
            }
        }
    }
}

// ---------------- global_add_pool (batch sorted -> run-length + atomics) --------

__global__ void pool_kernel(const ushort* __restrict__ hb, const int* __restrict__ batch,
                            float* __restrict__ pooled, int n) {
    const int lane = threadIdx.x & 63;
    const int wid  = threadIdx.x >> 6;
    const int wave = blockIdx.x * 4 + wid;
    const int nwaves = gridDim.x * 4;
    const int per = (n + nwaves - 1) / nwaves;
    const int a = wave * per;
    const int b = min(a + per, n);
    if (a >= b) return;
    int cur = batch[a];
    float sum = 0.0f;
    for (int i = a; i < b; ++i) {
        int g = batch[i];
        if (g != cur) {
            atomicAdd(&pooled[cur * DIM + lane], sum);
            sum = 0.0f;
            cur = g;
        }
        sum += __uint_as_float(((uint)hb[(size_t)i * DIM + lane]) << 16);
    }
    atomicAdd(&pooled[cur * DIM + lane], sum);
}

// ---------------- head: relu(pooled@lin1+b1) @ lin2 + b2 ----------------

__global__ void head_kernel(const float* __restrict__ pooled,
                            const float* __restrict__ w1, const float* __restrict__ b1,
                            const float* __restrict__ w2, const float* __restrict__ b2,
                            float* __restrict__ out) {
    const int g = blockIdx.x;
    const int lane = threadIdx.x;  // 64 threads = 1 wave
    __shared__ float pl[DIM];
    __shared__ float y1l[DIM];
    pl[lane] = pooled[g * DIM + lane];
    __syncthreads();
    float y = b1[lane];
#pragma unroll
    for (int d = 0; d < DIM; ++d) y += pl[d] * w1[d * DIM + lane];
    y1l[lane] = fmaxf(y, 0.0f);
    __syncthreads();
    if (lane < OUT_DIM) {
        float y2 = b2[lane];
#pragma unroll
        for (int d = 0; d < DIM; ++d) y2 += y1l[d] * w2[d * OUT_DIM + lane];
        out[g * OUT_DIM + lane] = y2;
    }
}

// ---------------- launch ----------------

extern "C" void kernel_launch(void* const* d_in, const int* in_sizes, int n_in,
                              void* d_out, int out_size, void* d_ws, size_t ws_size,
                              hipStream_t stream) {
    const float* x     = (const float*)d_in[0];
    const int*   eidx  = (const int*)  d_in[1];   // [2, N_EDGES]: src row then dst row
    const int*   batch = (const int*)  d_in[2];
    const float* W1    = (const float*)d_in[3];
    const float* b1    = (const float*)d_in[4];
    const float* gamma = (const float*)d_in[5];
    const float* beta  = (const float*)d_in[6];
    const float* rmean = (const float*)d_in[7];
    const float* rvar  = (const float*)d_in[8];
    const float* W2    = (const float*)d_in[9];
    const float* b2    = (const float*)d_in[10];
    const float* l1w   = (const float*)d_in[11];
    const float* l1b   = (const float*)d_in[12];
    const float* l2w   = (const float*)d_in[13];
    const float* l2b   = (const float*)d_in[14];
    float* out = (float*)d_out;

    // workspace layout (int-element offsets; 16B alignment preserved)
    const size_t C8 = (size_t)N_CHUNKS * N_RANGES * RANGE_SIZE;   // 3,670,016
    const size_t B8 = (size_t)N_CHUNKS * NODE_PAD;                // 3,670,016
    int* counts8   = (int*)d_ws;
    int* row_ptr   = counts8   + C8;              // 100352
    int* blockSums = row_ptr   + 100352;          // 256
    int* blockOffs = blockSums + 256;             // 256
    int* base8     = blockOffs + 256;             // B8
    int* col_idx   = base8     + B8;              // 1600000
    uint4* Wp      = (uint4*)(col_idx + 1600000); // 5120 uint4 = 80KB
    ushort* tb     = (ushort*)(Wp + 5120);        // 100000*64 bf16 (12.8MB)
    ushort* hb     = tb + (size_t)N_NODES * DIM;  // 100000*64 bf16 (12.8MB)
    float* pooled  = (float*)(hb + (size_t)N_NODES * DIM);   // 128*64 fp32

    const int* srcp = eidx;
    const int* dstp = eidx + N_EDGES;

    hipMemsetAsync(pooled, 0, N_GRAPHS * DIM * sizeof(float), stream);

    cvt_kernel<<<(N_NODES * DIM / 4 + 255) / 256, 256, 0, stream>>>(x, hb, N_NODES * DIM / 4);
    repack_kernel<<<1, 640, 0, stream>>>(W1, W2, Wp);
    histo_kernel<<<N_CHUNKS * 8, 1024, 0, stream>>>(dstp, counts8);
    scanA_kernel<<<SCAN_NB, 256, 0, stream>>>(counts8, blockSums, N_NODES);
    scanB_kernel<<<1, 256, 0, stream>>>(blockSums, blockOffs, row_ptr);
    scanC_kernel<<<SCAN_NB, 256, 0, stream>>>(counts8, blockOffs, row_ptr, base8, N_NODES);
    fill_kernel<<<N_CHUNKS * 8, 1024, 0, stream>>>(srcp, dstp, base8, col_idx);

    const int agg_blocks = ((N_NODES + 7) / 8 * 64 + 255) / 256;  // 8 nodes per wave
    const int ntiles = N_NODES / 16;                               // 6250 exact

    for (int l = 0; l < 5; ++l) {
        agg_kernel<<<agg_blocks, 256, 0, stream>>>(hb, tb, row_ptr, col_idx, N_NODES);
        mlp_kernel<<<512, 256, 0, stream>>>(
            tb, hb, Wp + (size_t)l * 2 * 8 * 64,
            b1 + (size_t)l * DIM, gamma + (size_t)l * DIM, beta + (size_t)l * DIM,
            rmean + (size_t)l * DIM, rvar + (size_t)l * DIM, b2 + (size_t)l * DIM, ntiles);
    }
    pool_kernel<<<2048, 256, 0, stream>>>(hb, batch, pooled, N_NODES);
    head_kernel<<<N_GRAPHS, 64, 0, stream>>>(pooled, l1w, l1b, l2w, l2b, out);
}

// Round 12
// 409.439 us; speedup vs baseline: 1.3575x; 1.3575x over previous
//
#include <hip/hip_runtime.h>

#define N_NODES  100000
#define N_EDGES  1600000
#define DIM      64
#define N_GRAPHS 128
#define OUT_DIM  10
#define SCAN_NB    196
#define SCAN_CHUNK 512      // 196*512 = 100352 >= N_NODES
#define RANGE_BITS 14
#define RANGE_SIZE 16384    // nodes per dst-range
#define N_RANGES   7        // 7*16384 = 114688 >= N_NODES
#define N_CHUNKS   32
#define CHUNK_EDGES (N_EDGES / N_CHUNKS)   // 50000
#define NODE_PAD   (N_RANGES * RANGE_SIZE) // 114688

typedef unsigned int uint;
typedef unsigned short ushort;
typedef __attribute__((ext_vector_type(8))) short short8;   // 8 bf16 = 4 VGPRs
typedef __attribute__((ext_vector_type(4))) float f32x4;

__device__ __forceinline__ uint f2bf(float x) {   // fp32 -> bf16 bits (RNE)
    uint b = __float_as_uint(x);
    b += 0x7fffu + ((b >> 16) & 1u);
    return b >> 16;
}

// ---------------- CSR build, NO global atomics, XCD-co-located chunks ----------
// WG mapping: c = blockIdx % 32, r = blockIdx / 32. XCD = blockIdx % 8 = c % 8,
// so all 8 range-WGs of a chunk run on ONE XCD -> chunk's dst/src fetched from
// HBM once, re-read as L2 hits.

__global__ __launch_bounds__(1024) void histo_kernel(const int* __restrict__ dst,
                                                     int* __restrict__ counts8) {
    __shared__ int lds[RANGE_SIZE];
    const int c = blockIdx.x & (N_CHUNKS - 1);
    const int r = blockIdx.x >> 5;
    if (r >= N_RANGES) return;
    for (int j = threadIdx.x; j < RANGE_SIZE; j += 1024) lds[j] = 0;
    __syncthreads();
    const int beg = c * CHUNK_EDGES, end = beg + CHUNK_EDGES;
    for (int i = beg + threadIdx.x; i < end; i += 1024) {
        int d = dst[i];
        if ((d >> RANGE_BITS) == r) atomicAdd(&lds[d & (RANGE_SIZE - 1)], 1);
    }
    __syncthreads();
    int* outp = counts8 + (c * N_RANGES + r) * RANGE_SIZE;   // contiguous 64KB dump
    for (int j = threadIdx.x; j < RANGE_SIZE; j += 1024) outp[j] = lds[j];
}

__global__ void scanA_kernel(const int* __restrict__ counts8, int* __restrict__ blockSums, int n) {
    __shared__ int red[256];
    const int b = blockIdx.x, t = threadIdx.x;
    int s = 0;
#pragma unroll
    for (int k = 0; k < 2; ++k) {
        const int node = b * SCAN_CHUNK + t * 2 + k;
        if (node < n) {
            const int r = node >> RANGE_BITS, jj = node & (RANGE_SIZE - 1);
            for (int c = 0; c < N_CHUNKS; ++c)
                s += counts8[(c * N_RANGES + r) * RANGE_SIZE + jj];
        }
    }
    red[t] = s;
    __syncthreads();
    for (int off = 128; off > 0; off >>= 1) {
        if (t < off) red[t] += red[t + off];
        __syncthreads();
    }
    if (t == 0) blockSums[b] = red[0];
}

__global__ void scanB_kernel(const int* __restrict__ blockSums, int* __restrict__ blockOffs,
                             int* __restrict__ row_ptr) {
    __shared__ int sc[256];
    const int t = threadIdx.x;
    const int v = (t < SCAN_NB) ? blockSums[t] : 0;
    sc[t] = v;
    __syncthreads();
    for (int off = 1; off < 256; off <<= 1) {
        int u = (t >= off) ? sc[t - off] : 0;
        __syncthreads();
        sc[t] += u;
        __syncthreads();
    }
    if (t < SCAN_NB) blockOffs[t] = sc[t] - v;   // exclusive block offset
    if (t == 255) row_ptr[N_NODES] = sc[255];    // total == N_EDGES
}

// row_ptr + per-chunk slot bases base8[c][node]
__global__ void scanC_kernel(const int* __restrict__ counts8, const int* __restrict__ blockOffs,
                             int* __restrict__ row_ptr, int* __restrict__ base8, int n) {
    __shared__ int sc[256];
    const int b = blockIdx.x, t = threadIdx.x;
    const int node0 = b * SCAN_CHUNK + t * 2;
    int cnt0[N_CHUNKS], cnt1[N_CHUNKS];
    int tot0 = 0, tot1 = 0;
    if (node0 < n) {
        const int r = node0 >> RANGE_BITS, jj = node0 & (RANGE_SIZE - 1);
        for (int c = 0; c < N_CHUNKS; ++c) {
            cnt0[c] = counts8[(c * N_RANGES + r) * RANGE_SIZE + jj];
            tot0 += cnt0[c];
        }
    }
    if (node0 + 1 < n) {
        const int r = (node0 + 1) >> RANGE_BITS, jj = (node0 + 1) & (RANGE_SIZE - 1);
        for (int c = 0; c < N_CHUNKS; ++c) {
            cnt1[c] = counts8[(c * N_RANGES + r) * RANGE_SIZE + jj];
            tot1 += cnt1[c];
        }
    }
    const int s = tot0 + tot1;
    sc[t] = s;
    __syncthreads();
    for (int off = 1; off < 256; off <<= 1) {
        int u = (t >= off) ? sc[t - off] : 0;
        __syncthreads();
        sc[t] += u;
        __syncthreads();
    }
    const int pre = blockOffs[b] + sc[t] - s;    // exclusive prefix for node0
    if (node0 < n) {
        row_ptr[node0] = pre;
        int run = pre;
        for (int c = 0; c < N_CHUNKS; ++c) { base8[c * NODE_PAD + node0] = run; run += cnt0[c]; }
    }
    if (node0 + 1 < n) {
        const int pre1 = pre + tot0;
        row_ptr[node0 + 1] = pre1;
        int run = pre1;
        for (int c = 0; c < N_CHUNKS; ++c) { base8[c * NODE_PAD + node0 + 1] = run; run += cnt1[c]; }
    }
}

__global__ __launch_bounds__(1024) void fill_kernel(const int* __restrict__ src,
                                                    const int* __restrict__ dst,
                                                    const int* __restrict__ base8,
                                                    int* __restrict__ col_idx) {
    __shared__ int lds[RANGE_SIZE];
    const int c = blockIdx.x & (N_CHUNKS - 1);
    const int r = blockIdx.x >> 5;
    if (r >= N_RANGES) return;
    const int* bp = base8 + c * NODE_PAD + r * RANGE_SIZE;
    for (int j = threadIdx.x; j < RANGE_SIZE; j += 1024) lds[j] = bp[j];
    __syncthreads();
    const int beg = c * CHUNK_EDGES, end = beg + CHUNK_EDGES;
    for (int i = beg + threadIdx.x; i < end; i += 1024) {
        int d = dst[i];
        if ((d >> RANGE_BITS) == r) {
            int pos = atomicAdd(&lds[d & (RANGE_SIZE - 1)], 1);
            col_idx[pos] = src[i];
        }
    }
}

// ---------------- x (fp32) -> bf16 rows ----------------

__global__ void cvt_kernel(const float* __restrict__ x, ushort* __restrict__ xb, int n4) {
    int idx = blockIdx.x * blockDim.x + threadIdx.x;
    if (idx >= n4) return;
    float4 v = ((const float4*)x)[idx];
    uint2 o;
    o.x = f2bf(v.x) | (f2bf(v.y) << 16);
    o.y = f2bf(v.z) | (f2bf(v.w) << 16);
    ((uint2*)xb)[idx] = o;
}

// ---------------- Weight repack: MFMA fragment layouts, once per launch ----------

__global__ void repack_kernel(const float* __restrict__ W1, const float* __restrict__ W2,
                              uint4* __restrict__ Wp) {
    const int wave = (blockIdx.x * blockDim.x + threadIdx.x) >> 6;
    if (wave >= 10) return;
    const int layer = wave >> 1;
    const float* W = (wave & 1) ? (W2 + layer * 4096) : (W1 + layer * 4096);
    const int lane = threadIdx.x & 63;
    const int n15 = lane & 15, quad = lane >> 4;
#pragma unroll
    for (int f = 0; f < 8; ++f) {
        const int outer = f >> 1, h = f & 1;
        uint p[4];
#pragma unroll
        for (int pj = 0; pj < 4; ++pj) {
            const int k0 = h * 32 + quad * 8 + 2 * pj;
            uint lo = f2bf(W[k0 * 64 + outer * 16 + n15]);
            uint hi = f2bf(W[(k0 + 1) * 64 + outer * 16 + n15]);
            p[pj] = lo | (hi << 16);
        }
        Wp[(wave * 8 + f) * 64 + lane] = make_uint4(p[0], p[1], p[2], p[3]);
    }
}

// ---------------- Aggregation: tb[i] = hb[i] + sum_{j in N(i)} hb[j] -> bf16 ------
// GROUP-PER-NODE: 8 lanes/node, 8 nodes/wave; unroll 8 -> 8 dwordx4 gathers in
// flight. NO min-waves launch bound: R11's (256,8) squeezed VGPR to 32 and the
// unroll spilled to scratch (FETCH 141MB / WRITE 97MB per dispatch, 64.6us).
// Let the allocator keep the working set in ~90 VGPRs at 4-5 waves/SIMD.

__device__ __forceinline__ void add_unpack(float acc[8], uint4 v) {
    acc[0] += __uint_as_float(v.x << 16);
    acc[1] += __uint_as_float(v.x & 0xffff0000u);
    acc[2] += __uint_as_float(v.y << 16);
    acc[3] += __uint_as_float(v.y & 0xffff0000u);
    acc[4] += __uint_as_float(v.z << 16);
    acc[5] += __uint_as_float(v.z & 0xffff0000u);
    acc[6] += __uint_as_float(v.w << 16);
    acc[7] += __uint_as_float(v.w & 0xffff0000u);
}

__global__ __launch_bounds__(256) void agg_kernel(
    const ushort* __restrict__ hb, ushort* __restrict__ tb,
    const int* __restrict__ row_ptr, const int* __restrict__ col_idx, int n)
{
    const uint4* __restrict__ hb4 = (const uint4*)hb;   // row = 8 uint4
    const int lane = threadIdx.x & 63;
    const int g = lane >> 3;     // node slot 0..7 within wave
    const int q = lane & 7;      // 16B chunk 0..7 within row
    const int wave = (blockIdx.x * blockDim.x + threadIdx.x) >> 6;
    const int i = wave * 8 + g;
    if (i >= n) return;
    const int rp0 = row_ptr[i];
    const int deg = row_ptr[i + 1] - rp0;

    float acc[8];
    {   // self term (eps = 0) — safe in init: no cross-lane reduction follows
        uint4 v = hb4[(size_t)i * 8 + q];
        acc[0] = __uint_as_float(v.x << 16);
        acc[1] = __uint_as_float(v.x & 0xffff0000u);
        acc[2] = __uint_as_float(v.y << 16);
        acc[3] = __uint_as_float(v.y & 0xffff0000u);
        acc[4] = __uint_as_float(v.z << 16);
        acc[5] = __uint_as_float(v.z & 0xffff0000u);
        acc[6] = __uint_as_float(v.w << 16);
        acc[7] = __uint_as_float(v.w & 0xffff0000u);
    }

    int e = 0;
    for (; e + 8 <= deg; e += 8) {   // 8 gathers in flight per group
        int ix[8];
#pragma unroll
        for (int k = 0; k < 8; ++k) ix[k] = col_idx[rp0 + e + k];
        uint4 v[8];
#pragma unroll
        for (int k = 0; k < 8; ++k) v[k] = hb4[(size_t)ix[k] * 8 + q];
#pragma unroll
        for (int k = 0; k < 8; ++k) add_unpack(acc, v[k]);
    }
    if (e + 4 <= deg) {
        int ix[4];
#pragma unroll
        for (int k = 0; k < 4; ++k) ix[k] = col_idx[rp0 + e + k];
        uint4 v[4];
#pragma unroll
        for (int k = 0; k < 4; ++k) v[k] = hb4[(size_t)ix[k] * 8 + q];
#pragma unroll
        for (int k = 0; k < 4; ++k) add_unpack(acc, v[k]);
        e += 4;
    }
    for (; e < deg; ++e) {
        int ix = col_idx[rp0 + e];
        uint4 v = hb4[(size_t)ix * 8 + q];
        add_unpack(acc, v);
    }

    uint4 o;   // pack 8 fp32 -> 8 bf16 (dims q*8 .. q*8+7)
    o.x = f2bf(acc[0]) | (f2bf(acc[1]) << 16);
    o.y = f2bf(acc[2]) | (f2bf(acc[3]) << 16);
    o.z = f2bf(acc[4]) | (f2bf(acc[5]) << 16);
    o.w = f2bf(acc[6]) | (f2bf(acc[7]) << 16);
    ((uint4*)tb)[(size_t)i * 8 + q] = o;
}

// ---------------- MLP via MFMA (R7 structure, unchanged) ----------------

__global__ __launch_bounds__(256) void mlp_kernel(
    const ushort* __restrict__ tb, ushort* __restrict__ hb,
    const uint4* __restrict__ Wp,   // layer frags: [0..7]=W1^T, [8..15]=W2
    const float* __restrict__ b1, const float* __restrict__ gamma,
    const float* __restrict__ beta, const float* __restrict__ rmean,
    const float* __restrict__ rvar, const float* __restrict__ b2, int ntiles)
{
    __shared__ __align__(16) ushort U[4][16][72];   // stride 72 breaks pow-2 banks
    const int lane = threadIdx.x & 63;
    const int wid  = threadIdx.x >> 6;
    const int n15  = lane & 15, quad = lane >> 4;

    short8 w1f[8], w2f[8];
    const short8* Wp8 = (const short8*)Wp;
#pragma unroll
    for (int f = 0; f < 8; ++f) {
        w1f[f] = Wp8[f * 64 + lane];
        w2f[f] = Wp8[(8 + f) * 64 + lane];
    }
    f32x4 sc[4], sh[4];
#pragma unroll
    for (int mt = 0; mt < 4; ++mt) {
        const int j0 = mt * 16 + quad * 4;
#pragma unroll
        for (int r = 0; r < 4; ++r) {
            float s = gamma[j0 + r] * rsqrtf(rvar[j0 + r] + 1e-5f);
            sc[mt][r] = s;
            sh[mt][r] = (b1[j0 + r] - rmean[j0 + r]) * s + beta[j0 + r];
        }
    }
    float bb2[4];
#pragma unroll
    for (int tc = 0; tc < 4; ++tc) bb2[tc] = b2[tc * 16 + n15];

    const int wave = blockIdx.x * 4 + wid;
    const int nwaves = gridDim.x * 4;
    for (int tile = wave; tile < ntiles; tile += nwaves) {
        const int nb = tile * 16;
        const short8* trow = (const short8*)(tb + (size_t)(nb + n15) * 64);
        short8 t0 = trow[quad];        // k = 0..31 half
        short8 t1 = trow[4 + quad];    // k = 32..63 half

        f32x4 c1[4];
#pragma unroll
        for (int mt = 0; mt < 4; ++mt) {
            c1[mt] = (f32x4){0.f, 0.f, 0.f, 0.f};
            c1[mt] = __builtin_amdgcn_mfma_f32_16x16x32_bf16(w1f[mt * 2 + 0], t0, c1[mt], 0, 0, 0);
            c1[mt] = __builtin_amdgcn_mfma_f32_16x16x32_bf16(w1f[mt * 2 + 1], t1, c1[mt], 0, 0, 0);
        }
#pragma unroll
        for (int mt = 0; mt < 4; ++mt) {
            float u0 = fmaxf(c1[mt][0] * sc[mt][0] + sh[mt][0], 0.f);
            float u1 = fmaxf(c1[mt][1] * sc[mt][1] + sh[mt][1], 0.f);
            float u2 = fmaxf(c1[mt][2] * sc[mt][2] + sh[mt][2], 0.f);
            float u3 = fmaxf(c1[mt][3] * sc[mt][3] + sh[mt][3], 0.f);
            uint2 pk;
            pk.x = f2bf(u0) | (f2bf(u1) << 16);
            pk.y = f2bf(u2) | (f2bf(u3) << 16);
            *(uint2*)&U[wid][n15][mt * 16 + quad * 4] = pk;
        }
        __threadfence_block();
        short8 u0 = *(const short8*)&U[wid][n15][quad * 8];
        short8 u1 = *(const short8*)&U[wid][n15][32 + quad * 8];

        f32x4 c2[4];
#pragma unroll
        for (int tc = 0; tc < 4; ++tc) {
            c2[tc] = (f32x4){0.f, 0.f, 0.f, 0.f};
            c2[tc] = __builtin_amdgcn_mfma_f32_16x16x32_bf16(u0, w2f[tc * 2 + 0], c2[tc], 0, 0, 0);
            c2[tc] = __builtin_amdgcn_mfma_f32_16x16x32_bf16(u1, w2f[tc * 2 + 1], c2[tc], 0, 0, 0);
        }
#pragma unroll
        for (int tc = 0; tc < 4; ++tc) {
#pragma unroll
            for (int r = 0; r < 4; ++r) {
                float v = fmaxf(c2[tc][r] + bb2[tc], 0.f);
                hb[(size_t)(nb + quad * 4 + r) * 64 + tc * 16 + n15] = (ushort)f2bf(v);
            }
        }
    }
}

// ---------------- global_add_pool (batch sorted -> run-length + atomics) --------

__global__ void pool_kernel(const ushort* __restrict__ hb, const int* __restrict__ batch,
                            float* __restrict__ pooled, int n) {
    const int lane = threadIdx.x & 63;
    const int wid  = threadIdx.x >> 6;
    const int wave = blockIdx.x * 4 + wid;
    const int nwaves = gridDim.x * 4;
    const int per = (n + nwaves - 1) / nwaves;
    const int a = wave * per;
    const int b = min(a + per, n);
    if (a >= b) return;
    int cur = batch[a];
    float sum = 0.0f;
    for (int i = a; i < b; ++i) {
        int g = batch[i];
        if (g != cur) {
            atomicAdd(&pooled[cur * DIM + lane], sum);
            sum = 0.0f;
            cur = g;
        }
        sum += __uint_as_float(((uint)hb[(size_t)i * DIM + lane]) << 16);
    }
    atomicAdd(&pooled[cur * DIM + lane], sum);
}

// ---------------- head: relu(pooled@lin1+b1) @ lin2 + b2 ----------------

__global__ void head_kernel(const float* __restrict__ pooled,
                            const float* __restrict__ w1, const float* __restrict__ b1,
                            const float* __restrict__ w2, const float* __restrict__ b2,
                            float* __restrict__ out) {
    const int g = blockIdx.x;
    const int lane = threadIdx.x;  // 64 threads = 1 wave
    __shared__ float pl[DIM];
    __shared__ float y1l[DIM];
    pl[lane] = pooled[g * DIM + lane];
    __syncthreads();
    float y = b1[lane];
#pragma unroll
    for (int d = 0; d < DIM; ++d) y += pl[d] * w1[d * DIM + lane];
    y1l[lane] = fmaxf(y, 0.0f);
    __syncthreads();
    if (lane < OUT_DIM) {
        float y2 = b2[lane];
#pragma unroll
        for (int d = 0; d < DIM; ++d) y2 += y1l[d] * w2[d * OUT_DIM + lane];
        out[g * OUT_DIM + lane] = y2;
    }
}

// ---------------- launch ----------------

extern "C" void kernel_launch(void* const* d_in, const int* in_sizes, int n_in,
                              void* d_out, int out_size, void* d_ws, size_t ws_size,
                              hipStream_t stream) {
    const float* x     = (const float*)d_in[0];
    const int*   eidx  = (const int*)  d_in[1];   // [2, N_EDGES]: src row then dst row
    const int*   batch = (const int*)  d_in[2];
    const float* W1    = (const float*)d_in[3];
    const float* b1    = (const float*)d_in[4];
    const float* gamma = (const float*)d_in[5];
    const float* beta  = (const float*)d_in[6];
    const float* rmean = (const float*)d_in[7];
    const float* rvar  = (const float*)d_in[8];
    const float* W2    = (const float*)d_in[9];
    const float* b2    = (const float*)d_in[10];
    const float* l1w   = (const float*)d_in[11];
    const float* l1b   = (const float*)d_in[12];
    const float* l2w   = (const float*)d_in[13];
    const float* l2b   = (const float*)d_in[14];
    float* out = (float*)d_out;

    // workspace layout (int-element offsets; 16B alignment preserved)
    const size_t C8 = (size_t)N_CHUNKS * N_RANGES * RANGE_SIZE;   // 3,670,016
    const size_t B8 = (size_t)N_CHUNKS * NODE_PAD;                // 3,670,016
    int* counts8   = (int*)d_ws;
    int* row_ptr   = counts8   + C8;              // 100352
    int* blockSums = row_ptr   + 100352;          // 256
    int* blockOffs = blockSums + 256;             // 256
    int* base8     = blockOffs + 256;             // B8
    int* col_idx   = base8     + B8;              // 1600000
    uint4* Wp      = (uint4*)(col_idx + 1600000); // 5120 uint4 = 80KB
    ushort* tb     = (ushort*)(Wp + 5120);        // 100000*64 bf16 (12.8MB)
    ushort* hb     = tb + (size_t)N_NODES * DIM;  // 100000*64 bf16 (12.8MB)
    float* pooled  = (float*)(hb + (size_t)N_NODES * DIM);   // 128*64 fp32

    const int* srcp = eidx;
    const int* dstp = eidx + N_EDGES;

    hipMemsetAsync(pooled, 0, N_GRAPHS * DIM * sizeof(float), stream);

    cvt_kernel<<<(N_NODES * DIM / 4 + 255) / 256, 256, 0, stream>>>(x, hb, N_NODES * DIM / 4);
    repack_kernel<<<1, 640, 0, stream>>>(W1, W2, Wp);
    histo_kernel<<<N_CHUNKS * 8, 1024, 0, stream>>>(dstp, counts8);
    scanA_kernel<<<SCAN_NB, 256, 0, stream>>>(counts8, blockSums, N_NODES);
    scanB_kernel<<<1, 256, 0, stream>>>(blockSums, blockOffs, row_ptr);
    scanC_kernel<<<SCAN_NB, 256, 0, stream>>>(counts8, blockOffs, row_ptr, base8, N_NODES);
    fill_kernel<<<N_CHUNKS * 8, 1024, 0, stream>>>(srcp, dstp, base8, col_idx);

    const int agg_blocks = ((N_NODES + 7) / 8 * 64 + 255) / 256;  // 8 nodes per wave
    const int ntiles = N_NODES / 16;                               // 6250 exact

    for (int l = 0; l < 5; ++l) {
        agg_kernel<<<agg_blocks, 256, 0, stream>>>(hb, tb, row_ptr, col_idx, N_NODES);
        mlp_kernel<<<512, 256, 0, stream>>>(
            tb, hb, Wp + (size_t)l * 2 * 8 * 64,
            b1 + (size_t)l * DIM, gamma + (size_t)l * DIM, beta + (size_t)l * DIM,
            rmean + (size_t)l * DIM, rvar + (size_t)l * DIM, b2 + (size_t)l * DIM, ntiles);
    }
    pool_kernel<<<2048, 256, 0, stream>>>(hb, batch, pooled, N_NODES);
    head_kernel<<<N_GRAPHS, 64, 0, stream>>>(pooled, l1w, l1b, l2w, l2b, out);
}